// Round 2
// baseline (783.015 us; speedup 1.0000x reference)
//
#include <hip/hip_runtime.h>
#include <hip/hip_bf16.h>

// q = x@Wq^T; k = y@Wk^T; v = y@Wv^T; out = strict_lower(q@k^T * D^-0.5) @ v
// NX=NY=8192, C=2048, D=512. bf16 MFMA everywhere.
// ws: q[8192*512] k[8192*512] v[8192*512] vT[512*8192] bf16 = 32 MB.

typedef __bf16 bf16x8 __attribute__((ext_vector_type(8)));
typedef float f32x4 __attribute__((ext_vector_type(4)));

#define MFMA16(a, b, c) __builtin_amdgcn_mfma_f32_16x16x32_bf16(a, b, c, 0, 0, 0)

constexpr float SCALE = 0.04419417382415922f; // 1/sqrt(512)

__device__ inline bf16x8 pack8(float4 a, float4 b) {
    bf16x8 r;
    r[0] = (__bf16)a.x; r[1] = (__bf16)a.y; r[2] = (__bf16)a.z; r[3] = (__bf16)a.w;
    r[4] = (__bf16)b.x; r[5] = (__bf16)b.y; r[6] = (__bf16)b.z; r[7] = (__bf16)b.w;
    return r;
}

// ---------------------------------------------------------------------------
// Stage 1: all three GEMMs in one launch (z selects), 768 blocks = 3/CU.
// C_bf16[8192,512] = A_f32[8192,2048] @ B_f32[512,2048]^T, 128x128 tile, BK=64.
// ---------------------------------------------------------------------------
__global__ __launch_bounds__(256, 3) void gemm_qkv3(
    const float* __restrict__ x, const float* __restrict__ y,
    const float* __restrict__ Wq, const float* __restrict__ Wk,
    const float* __restrict__ Wv, __bf16* __restrict__ qo,
    __bf16* __restrict__ ko, __bf16* __restrict__ vo)
{
    constexpr int K = 2048, N = 512;
    __shared__ __bf16 As[128][72];
    __shared__ __bf16 Bs[128][72];

    const int z = blockIdx.z;
    const float* A = (z == 0) ? x : y;
    const float* B = (z == 0) ? Wq : (z == 1) ? Wk : Wv;
    __bf16* C = (z == 0) ? qo : (z == 1) ? ko : vo;

    const int tid  = threadIdx.x;
    const int wave = tid >> 6, lane = tid & 63;
    const int fr = lane & 15, fq = lane >> 4;
    const int m0 = blockIdx.x * 128;
    const int n0 = blockIdx.y * 128;
    const int wr = (wave >> 1) * 64, wc = (wave & 1) * 64;
    const int srow = tid >> 1;            // 0..127
    const int scol = (tid & 1) * 32;      // 0 or 32

    f32x4 acc[4][4];
#pragma unroll
    for (int a = 0; a < 4; ++a)
#pragma unroll
        for (int b = 0; b < 4; ++b) acc[a][b] = f32x4{0.f, 0.f, 0.f, 0.f};

    const float* ap = A + (size_t)(m0 + srow) * K + scol;
    const float* bp = B + (size_t)(n0 + srow) * K + scol;

    for (int kk = 0; kk < K; kk += 64) {
        float4 av[8], bv[8];
#pragma unroll
        for (int u = 0; u < 8; ++u) av[u] = ((const float4*)(ap + kk))[u];
#pragma unroll
        for (int u = 0; u < 8; ++u) bv[u] = ((const float4*)(bp + kk))[u];
        __syncthreads();
#pragma unroll
        for (int u = 0; u < 4; ++u) {
            *(bf16x8*)&As[srow][scol + u * 8] = pack8(av[2 * u], av[2 * u + 1]);
            *(bf16x8*)&Bs[srow][scol + u * 8] = pack8(bv[2 * u], bv[2 * u + 1]);
        }
        __syncthreads();
#pragma unroll
        for (int ks = 0; ks < 2; ++ks) {
            bf16x8 af[4], bf[4];
#pragma unroll
            for (int rt = 0; rt < 4; ++rt)
                af[rt] = *(const bf16x8*)&As[wr + rt * 16 + fr][ks * 32 + fq * 8];
#pragma unroll
            for (int nt = 0; nt < 4; ++nt)
                bf[nt] = *(const bf16x8*)&Bs[wc + nt * 16 + fr][ks * 32 + fq * 8];
#pragma unroll
            for (int rt = 0; rt < 4; ++rt)
#pragma unroll
                for (int nt = 0; nt < 4; ++nt)
                    acc[rt][nt] = MFMA16(af[rt], bf[nt], acc[rt][nt]);
        }
    }

#pragma unroll
    for (int rt = 0; rt < 4; ++rt)
#pragma unroll
        for (int nt = 0; nt < 4; ++nt) {
            const int col = n0 + wc + nt * 16 + fr;
#pragma unroll
            for (int r = 0; r < 4; ++r) {
                const int row = m0 + wr + rt * 16 + fq * 4 + r;
                C[(size_t)row * N + col] = (__bf16)acc[rt][nt][r];
            }
        }
}

// ---------------------------------------------------------------------------
// Transpose v[8192,512] -> vT[512,8192] (bf16), 64x64 LDS tiles.
// ---------------------------------------------------------------------------
__global__ __launch_bounds__(256) void transpose_v(
    const ushort* __restrict__ v, ushort* __restrict__ vT)
{
    __shared__ ushort tile[64][72];
    const int t = threadIdx.x;
    const int r0 = blockIdx.x * 64;
    const int c0 = blockIdx.y * 64;
    const int lr = t >> 2;
    const int lc = (t & 3) * 16;

    union { float4 f[2]; ushort s[16]; } u;
    const float4* vp = (const float4*)(v + (size_t)(r0 + lr) * 512 + c0 + lc);
    u.f[0] = vp[0];
    u.f[1] = vp[1];
#pragma unroll
    for (int e = 0; e < 16; ++e) tile[lc + e][lr] = u.s[e];
    __syncthreads();
    float4* op = (float4*)(vT + (size_t)(c0 + lr) * 8192 + r0 + lc);
    op[0] = *(const float4*)&tile[lr][lc];
    op[1] = *(const float4*)&tile[lr][lc + 8];
}

// ---------------------------------------------------------------------------
// Stage 2 v2: fused masked-score + PV, fragments direct from global.
// Block: 256 thr (4 waves) = (row-tile i of 64 rows, g of 8).
// Per j2-iter: S[64 x 256] (two 128-col K-tiles), K=512 -> mask -> ps LDS ->
// O[64 x 512] += P @ V. Only 2 barriers / iter. O in regs across j2 loop.
// Wave: phase1 64x64 S cols (R4C4), phase2 64x128 O cols (R4C8).
// ---------------------------------------------------------------------------
__global__ __launch_bounds__(256, 3) void fused_av(
    const __bf16* __restrict__ q, const __bf16* __restrict__ k,
    const __bf16* __restrict__ vT, float* __restrict__ out)
{
    __shared__ __bf16 ps[64][264];   // row stride 528B = 33*16B (aligned, odd*4-word)

    const int tid  = threadIdx.x;
    const int wave = tid >> 6, lane = tid & 63;
    const int fr = lane & 15, fq = lane >> 4;
    const int bid = blockIdx.x;
    const int tt = bid >> 3, g = bid & 7;
    const int i = 127 - tt;          // heavy row-tiles dispatched first
    const int j2max = i >> 2;        // 256-col groups touching the lower triangle
    const int m0 = i * 64;

    f32x4 acc_o[4][8];
#pragma unroll
    for (int rt = 0; rt < 4; ++rt)
#pragma unroll
        for (int nt = 0; nt < 8; ++nt) acc_o[rt][nt] = f32x4{0.f, 0.f, 0.f, 0.f};

    for (int j2 = g; j2 <= j2max; j2 += 8) {
        // ---- phase 1: S[64 x 256] = Q_i @ K^T, frags direct from global ----
        f32x4 acc_s[4][4];
#pragma unroll
        for (int rt = 0; rt < 4; ++rt)
#pragma unroll
            for (int ct = 0; ct < 4; ++ct) acc_s[rt][ct] = f32x4{0.f, 0.f, 0.f, 0.f};

        const int c0 = j2 * 256 + wave * 64;  // this wave's S col base
#pragma unroll 4
        for (int c = 0; c < 16; ++c) {        // K = 512 in 32-chunks
            bf16x8 af[4], bf[4];
#pragma unroll
            for (int rt = 0; rt < 4; ++rt)
                af[rt] = *(const bf16x8*)(q + (size_t)(m0 + rt * 16 + fr) * 512 + c * 32 + fq * 8);
#pragma unroll
            for (int ct = 0; ct < 4; ++ct)
                bf[ct] = *(const bf16x8*)(k + (size_t)(c0 + ct * 16 + fr) * 512 + c * 32 + fq * 8);
#pragma unroll
            for (int rt = 0; rt < 4; ++rt)
#pragma unroll
                for (int ct = 0; ct < 4; ++ct)
                    acc_s[rt][ct] = MFMA16(af[rt], bf[ct], acc_s[rt][ct]);
        }

        __syncthreads();  // prev iter's ps reads complete
        // ---- mask + scale -> bf16 P in LDS ----
#pragma unroll
        for (int rt = 0; rt < 4; ++rt)
#pragma unroll
            for (int ct = 0; ct < 4; ++ct) {
                const int col = wave * 64 + ct * 16 + fr;
                const int gcol = j2 * 256 + col;
#pragma unroll
                for (int r = 0; r < 4; ++r) {
                    const int row = rt * 16 + fq * 4 + r;
                    const int grow = m0 + row;
                    float s = acc_s[rt][ct][r] * SCALE;
                    ps[row][col] = (__bf16)((gcol >= grow) ? 0.f : s);
                }
            }
        __syncthreads();

        // ---- phase 2: O[64 x 512] += P[64 x 256] @ V, V-frags from vT ----
#pragma unroll 2
        for (int c2 = 0; c2 < 8; ++c2) {      // 256-K in 32-chunks
            bf16x8 pf[4], vf[8];
#pragma unroll
            for (int rt = 0; rt < 4; ++rt)
                pf[rt] = *(const bf16x8*)&ps[rt * 16 + fr][c2 * 32 + fq * 8];
#pragma unroll
            for (int nt = 0; nt < 8; ++nt)
                vf[nt] = *(const bf16x8*)(vT + (size_t)(wave * 128 + nt * 16 + fr) * 8192
                                          + j2 * 256 + c2 * 32 + fq * 8);
#pragma unroll
            for (int rt = 0; rt < 4; ++rt)
#pragma unroll
                for (int nt = 0; nt < 8; ++nt)
                    acc_o[rt][nt] = MFMA16(pf[rt], vf[nt], acc_o[rt][nt]);
        }
    }

    if (g <= j2max) {
#pragma unroll
        for (int rt = 0; rt < 4; ++rt)
#pragma unroll
            for (int nt = 0; nt < 8; ++nt) {
                const int col = wave * 128 + nt * 16 + fr;
#pragma unroll
                for (int r = 0; r < 4; ++r) {
                    const int row = m0 + rt * 16 + fq * 4 + r;
                    atomicAdd(&out[(size_t)row * 512 + col], acc_o[rt][nt][r]);
                }
            }
    }
}

// ---------------------------------------------------------------------------
extern "C" void kernel_launch(void* const* d_in, const int* in_sizes, int n_in,
                              void* d_out, int out_size, void* d_ws, size_t ws_size,
                              hipStream_t stream) {
    const float* x  = (const float*)d_in[0];
    const float* y  = (const float*)d_in[1];
    const float* Wq = (const float*)d_in[2];
    const float* Wk = (const float*)d_in[3];
    const float* Wv = (const float*)d_in[4];
    float* out = (float*)d_out;

    const size_t QK = (size_t)8192 * 512;
    __bf16* q  = (__bf16*)d_ws;
    __bf16* k  = q + QK;
    __bf16* v  = k + QK;
    __bf16* vT = v + QK;

    hipMemsetAsync(d_out, 0, QK * sizeof(float), stream);

    gemm_qkv3<<<dim3(64, 4, 3), 256, 0, stream>>>(x, y, Wq, Wk, Wv, q, k, v);
    transpose_v<<<dim3(128, 8), 256, 0, stream>>>((const ushort*)v, (ushort*)vT);
    fused_av<<<1024, 256, 0, stream>>>(q, k, vT, out);
}

// Round 3
// 615.058 us; speedup vs baseline: 1.2731x; 1.2731x over previous
//
#include <hip/hip_runtime.h>
#include <hip/hip_bf16.h>

// q = x@Wq^T; k = y@Wk^T; v = y@Wv^T; out = strict_lower(q@k^T * D^-0.5) @ v
// NX=NY=8192, C=2048, D=512. bf16 MFMA everywhere.
// ws: q[8192*512] k[8192*512] v[8192*512] vT[512*8192] bf16 = 32 MB.

typedef __bf16 bf16x8 __attribute__((ext_vector_type(8)));
typedef float f32x4 __attribute__((ext_vector_type(4)));

#define MFMA16(a, b, c) __builtin_amdgcn_mfma_f32_16x16x32_bf16(a, b, c, 0, 0, 0)

constexpr float SCALE = 0.04419417382415922f; // 1/sqrt(512)

__device__ inline bf16x8 pack8(float4 a, float4 b) {
    bf16x8 r;
    r[0] = (__bf16)a.x; r[1] = (__bf16)a.y; r[2] = (__bf16)a.z; r[3] = (__bf16)a.w;
    r[4] = (__bf16)b.x; r[5] = (__bf16)b.y; r[6] = (__bf16)b.z; r[7] = (__bf16)b.w;
    return r;
}

// ---------------------------------------------------------------------------
// Stage 1: all three GEMMs in one launch (z selects).
// C_bf16[8192,512] = A_f32[8192,2048] @ B_f32[512,2048]^T, 128x128 tile, BK=64.
// v3: register-prefetch of next BK-chunk overlaps global latency with MFMA.
// ---------------------------------------------------------------------------
__global__ __launch_bounds__(256, 2) void gemm_qkv3(
    const float* __restrict__ x, const float* __restrict__ y,
    const float* __restrict__ Wq, const float* __restrict__ Wk,
    const float* __restrict__ Wv, __bf16* __restrict__ qo,
    __bf16* __restrict__ ko, __bf16* __restrict__ vo)
{
    constexpr int K = 2048, N = 512;
    __shared__ __bf16 As[128][72];
    __shared__ __bf16 Bs[128][72];

    const int z = blockIdx.z;
    const float* A = (z == 0) ? x : y;
    const float* B = (z == 0) ? Wq : (z == 1) ? Wk : Wv;
    __bf16* C = (z == 0) ? qo : (z == 1) ? ko : vo;

    const int tid  = threadIdx.x;
    const int wave = tid >> 6, lane = tid & 63;
    const int fr = lane & 15, fq = lane >> 4;
    const int m0 = blockIdx.x * 128;
    const int n0 = blockIdx.y * 128;
    const int wr = (wave >> 1) * 64, wc = (wave & 1) * 64;
    const int srow = tid >> 1;            // 0..127
    const int scol = (tid & 1) * 32;      // 0 or 32

    f32x4 acc[4][4];
#pragma unroll
    for (int a = 0; a < 4; ++a)
#pragma unroll
        for (int b = 0; b < 4; ++b) acc[a][b] = f32x4{0.f, 0.f, 0.f, 0.f};

    const float* ap = A + (size_t)(m0 + srow) * K + scol;
    const float* bp = B + (size_t)(n0 + srow) * K + scol;

    float4 av[8], bv[8];
#pragma unroll
    for (int u = 0; u < 8; ++u) av[u] = ((const float4*)ap)[u];
#pragma unroll
    for (int u = 0; u < 8; ++u) bv[u] = ((const float4*)bp)[u];

    for (int kk = 0; kk < K; kk += 64) {
        __syncthreads();
#pragma unroll
        for (int u = 0; u < 4; ++u) {
            *(bf16x8*)&As[srow][scol + u * 8] = pack8(av[2 * u], av[2 * u + 1]);
            *(bf16x8*)&Bs[srow][scol + u * 8] = pack8(bv[2 * u], bv[2 * u + 1]);
        }
        __syncthreads();
        if (kk + 64 < K) {   // prefetch next chunk; overlaps the MFMA section
#pragma unroll
            for (int u = 0; u < 8; ++u) av[u] = ((const float4*)(ap + kk + 64))[u];
#pragma unroll
            for (int u = 0; u < 8; ++u) bv[u] = ((const float4*)(bp + kk + 64))[u];
        }
#pragma unroll
        for (int ks = 0; ks < 2; ++ks) {
            bf16x8 af[4], bf[4];
#pragma unroll
            for (int rt = 0; rt < 4; ++rt)
                af[rt] = *(const bf16x8*)&As[wr + rt * 16 + fr][ks * 32 + fq * 8];
#pragma unroll
            for (int nt = 0; nt < 4; ++nt)
                bf[nt] = *(const bf16x8*)&Bs[wc + nt * 16 + fr][ks * 32 + fq * 8];
#pragma unroll
            for (int rt = 0; rt < 4; ++rt)
#pragma unroll
                for (int nt = 0; nt < 4; ++nt)
                    acc[rt][nt] = MFMA16(af[rt], bf[nt], acc[rt][nt]);
        }
    }

#pragma unroll
    for (int rt = 0; rt < 4; ++rt)
#pragma unroll
        for (int nt = 0; nt < 4; ++nt) {
            const int col = n0 + wc + nt * 16 + fr;
#pragma unroll
            for (int r = 0; r < 4; ++r) {
                const int row = m0 + wr + rt * 16 + fq * 4 + r;
                C[(size_t)row * N + col] = (__bf16)acc[rt][nt][r];
            }
        }
}

// ---------------------------------------------------------------------------
// Transpose v[8192,512] -> vT[512,8192] (bf16), 64x64 LDS tiles.
// ---------------------------------------------------------------------------
__global__ __launch_bounds__(256) void transpose_v(
    const ushort* __restrict__ v, ushort* __restrict__ vT)
{
    __shared__ ushort tile[64][72];
    const int t = threadIdx.x;
    const int r0 = blockIdx.x * 64;
    const int c0 = blockIdx.y * 64;
    const int lr = t >> 2;
    const int lc = (t & 3) * 16;

    union { float4 f[2]; ushort s[16]; } u;
    const float4* vp = (const float4*)(v + (size_t)(r0 + lr) * 512 + c0 + lc);
    u.f[0] = vp[0];
    u.f[1] = vp[1];
#pragma unroll
    for (int e = 0; e < 16; ++e) tile[lc + e][lr] = u.s[e];
    __syncthreads();
    float4* op = (float4*)(vT + (size_t)(c0 + lr) * 8192 + r0 + lc);
    op[0] = *(const float4*)&tile[lr][lc];
    op[1] = *(const float4*)&tile[lr][lc + 8];
}

// ---------------------------------------------------------------------------
// Stage 2 v3: fused masked-score + PV with LDS-staged Q/K.
// Block = 512 thr (8 waves), row-tile t (128 rows), split s of ceil((t+1)/8):
// windows j = s, s+nb, ... <= t, each 128 score-cols.
// Per window: phase1 S[128x128] (K=512, BK=128, 4 staged chunks, reg-prefetch),
// mask -> ps LDS (aliases qs/ks), phase2 O[128x512] += P @ V (V direct from vT).
// O held in registers across windows; one fp32 atomicAdd epilogue.
// LDS: qs[128][136] + ks[128][136] = 69632 B dynamic; ps aliases qs.
// ---------------------------------------------------------------------------
__global__ __launch_bounds__(512, 1) void fused_av(
    const __bf16* __restrict__ q, const __bf16* __restrict__ k,
    const __bf16* __restrict__ vT, float* __restrict__ out)
{
    extern __shared__ __bf16 smem[];
    __bf16 (*qs)[136] = (__bf16(*)[136])smem;                 // [128][136]
    __bf16 (*ks)[136] = (__bf16(*)[136])(smem + 128 * 136);   // [128][136]
    __bf16 (*ps)[136] = (__bf16(*)[136])smem;                 // alias qs (barrier-separated)

    const int tid  = threadIdx.x;
    const int wave = tid >> 6, lane = tid & 63;
    const int fr = lane & 15, fq = lane >> 4;
    const int wr = (wave >> 2) * 64;   // phase1/2 row base (0 or 64)
    const int wc = (wave & 3) * 32;    // phase1 col base
    const int oc = (wave & 3) * 128;   // phase2 O col base

    // block -> (t, s), heavy tiles (large t) first; sum of nb over t = 288
    int rem = blockIdx.x;
    int t = 63, nb;
    while (true) {
        nb = (t + 8) >> 3;             // ceil((t+1)/8)
        if (rem < nb) break;
        rem -= nb; --t;
    }
    const int s = rem;

    // staging map: thread -> 4 rows (r0+32u), 16B block blk (const per thread)
    const int r0  = tid >> 4;          // 0..31
    const int blk = tid & 15;          // 0..15

    f32x4 acc_o[4][8];
#pragma unroll
    for (int rt = 0; rt < 4; ++rt)
#pragma unroll
        for (int nt = 0; nt < 8; ++nt) acc_o[rt][nt] = f32x4{0.f, 0.f, 0.f, 0.f};

    for (int j = s; j <= t; j += nb) {
        // ---------------- phase 1: S[128x128] = Q_t @ K_j^T ----------------
        f32x4 acc_s[4][2];
#pragma unroll
        for (int rt = 0; rt < 4; ++rt)
#pragma unroll
            for (int ct = 0; ct < 2; ++ct) acc_s[rt][ct] = f32x4{0.f, 0.f, 0.f, 0.f};

        bf16x8 qreg[4], kreg[4];
#pragma unroll
        for (int u = 0; u < 4; ++u) {
            qreg[u] = *(const bf16x8*)(q + (size_t)(t * 128 + r0 + 32 * u) * 512 + blk * 8);
            kreg[u] = *(const bf16x8*)(k + (size_t)(j * 128 + r0 + 32 * u) * 512 + blk * 8);
        }

#pragma unroll
        for (int ii = 0; ii < 4; ++ii) {   // kk = ii*128
            __syncthreads();               // prev reads (frags or ps) done
#pragma unroll
            for (int u = 0; u < 4; ++u) {
                *(bf16x8*)&qs[r0 + 32 * u][blk * 8] = qreg[u];
                *(bf16x8*)&ks[r0 + 32 * u][blk * 8] = kreg[u];
            }
            __syncthreads();
            if (ii < 3) {                  // prefetch next chunk over MFMAs
                const int kk = (ii + 1) * 128;
#pragma unroll
                for (int u = 0; u < 4; ++u) {
                    qreg[u] = *(const bf16x8*)(q + (size_t)(t * 128 + r0 + 32 * u) * 512 + kk + blk * 8);
                    kreg[u] = *(const bf16x8*)(k + (size_t)(j * 128 + r0 + 32 * u) * 512 + kk + blk * 8);
                }
            }
#pragma unroll
            for (int ksC = 0; ksC < 4; ++ksC) {
                bf16x8 af[4], bfg[2];
#pragma unroll
                for (int rt = 0; rt < 4; ++rt)
                    af[rt] = *(const bf16x8*)&qs[wr + rt * 16 + fr][ksC * 32 + fq * 8];
#pragma unroll
                for (int ct = 0; ct < 2; ++ct)
                    bfg[ct] = *(const bf16x8*)&ks[wc + ct * 16 + fr][ksC * 32 + fq * 8];
#pragma unroll
                for (int rt = 0; rt < 4; ++rt)
#pragma unroll
                    for (int ct = 0; ct < 2; ++ct)
                        acc_s[rt][ct] = MFMA16(af[rt], bfg[ct], acc_s[rt][ct]);
            }
        }

        __syncthreads();   // all qs/ks frag reads done before ps (aliased) writes
        // ---------------- mask + scale -> bf16 P in LDS --------------------
#pragma unroll
        for (int rt = 0; rt < 4; ++rt)
#pragma unroll
            for (int ct = 0; ct < 2; ++ct) {
                const int col  = wc + ct * 16 + fr;
                const int gcol = j * 128 + col;
#pragma unroll
                for (int r = 0; r < 4; ++r) {
                    const int row  = wr + rt * 16 + fq * 4 + r;
                    const int grow = t * 128 + row;
                    ps[row][col] = (__bf16)((gcol >= grow) ? 0.f : acc_s[rt][ct][r] * SCALE);
                }
            }
        __syncthreads();

        // ---------------- phase 2: O[128x512] += P @ V_j -------------------
#pragma unroll
        for (int c2 = 0; c2 < 4; ++c2) {
            bf16x8 pf[4], vf[8];
#pragma unroll
            for (int nt = 0; nt < 8; ++nt)
                vf[nt] = *(const bf16x8*)(vT + (size_t)(oc + nt * 16 + fr) * 8192
                                          + j * 128 + c2 * 32 + fq * 8);
#pragma unroll
            for (int rt = 0; rt < 4; ++rt)
                pf[rt] = *(const bf16x8*)&ps[wr + rt * 16 + fr][c2 * 32 + fq * 8];
#pragma unroll
            for (int rt = 0; rt < 4; ++rt)
#pragma unroll
                for (int nt = 0; nt < 8; ++nt)
                    acc_o[rt][nt] = MFMA16(pf[rt], vf[nt], acc_o[rt][nt]);
        }
        // next window's first barrier separates these ps reads from qs writes
    }

    // epilogue: every block has >= 1 window (s < nb <= t+1)
#pragma unroll
    for (int rt = 0; rt < 4; ++rt)
#pragma unroll
        for (int nt = 0; nt < 8; ++nt) {
            const int col = oc + nt * 16 + fr;
#pragma unroll
            for (int r = 0; r < 4; ++r) {
                const int row = t * 128 + wr + rt * 16 + fq * 4 + r;
                atomicAdd(&out[(size_t)row * 512 + col], acc_o[rt][nt][r]);
            }
        }
}

// ---------------------------------------------------------------------------
extern "C" void kernel_launch(void* const* d_in, const int* in_sizes, int n_in,
                              void* d_out, int out_size, void* d_ws, size_t ws_size,
                              hipStream_t stream) {
    const float* x  = (const float*)d_in[0];
    const float* y  = (const float*)d_in[1];
    const float* Wq = (const float*)d_in[2];
    const float* Wk = (const float*)d_in[3];
    const float* Wv = (const float*)d_in[4];
    float* out = (float*)d_out;

    const size_t QK = (size_t)8192 * 512;
    __bf16* q  = (__bf16*)d_ws;
    __bf16* k  = q + QK;
    __bf16* v  = k + QK;
    __bf16* vT = v + QK;

    hipMemsetAsync(d_out, 0, QK * sizeof(float), stream);

    gemm_qkv3<<<dim3(64, 4, 3), 256, 0, stream>>>(x, y, Wq, Wk, Wv, q, k, v);
    transpose_v<<<dim3(128, 8), 256, 0, stream>>>((const ushort*)v, (ushort*)vT);

    const int fused_lds = 2 * 128 * 136 * sizeof(__bf16);  // 69632 B
    hipFuncSetAttribute((const void*)fused_av,
                        hipFuncAttributeMaxDynamicSharedMemorySize, fused_lds);
    fused_av<<<288, 512, fused_lds, stream>>>(q, k, vT, out);
}

// Round 4
// 367.625 us; speedup vs baseline: 2.1299x; 1.6731x over previous
//
#include <hip/hip_runtime.h>
#include <hip/hip_bf16.h>

// q = x@Wq^T; k = y@Wk^T; v = y@Wv^T; out = strict_lower(q@k^T * D^-0.5) @ v
// NX=NY=8192, C=2048, D=512. bf16 MFMA everywhere.
//
// v4 pipeline: convert(fp32->bf16) -> bf16 GEMM qkv -> transpose v ->
//   s_gemm (banded masked S, bf16, 2080 tiles) -> pv_gemm (K-split, atomics).
// ws (bf16 elems): q[4M] k[4M] v[4M] vT[4M] | xb[16M] yb[16M] wq[1M] wk[1M] wv[1M]
//   Sb[33.25M tiles] overlaps xb.. (dead after gemm). Peak 102 MB.

typedef __bf16 bf16x8 __attribute__((ext_vector_type(8)));
typedef float f32x4 __attribute__((ext_vector_type(4)));

#define MFMA16(a, b, c) __builtin_amdgcn_mfma_f32_16x16x32_bf16(a, b, c, 0, 0, 0)

constexpr float SCALE = 0.04419417382415922f; // 1/sqrt(512)

__device__ inline bf16x8 pack8(float4 a, float4 b) {
    bf16x8 r;
    r[0] = (__bf16)a.x; r[1] = (__bf16)a.y; r[2] = (__bf16)a.z; r[3] = (__bf16)a.w;
    r[4] = (__bf16)b.x; r[5] = (__bf16)b.y; r[6] = (__bf16)b.z; r[7] = (__bf16)b.w;
    return r;
}

// ---------------------------------------------------------------------------
// fp32 -> bf16 conversion, one launch. unit = 8 floats.
// x: 2097152 units, y: 2097152, Wq/Wk/Wv: 131072 each. total 4587520 = 17920*256
// ---------------------------------------------------------------------------
__global__ __launch_bounds__(256) void convert_all(
    const float* __restrict__ x, const float* __restrict__ y,
    const float* __restrict__ wqf, const float* __restrict__ wkf,
    const float* __restrict__ wvf, __bf16* __restrict__ xb,
    __bf16* __restrict__ yb, __bf16* __restrict__ wqb,
    __bf16* __restrict__ wkb, __bf16* __restrict__ wvb)
{
    size_t uid = (size_t)blockIdx.x * 256 + threadIdx.x;
    const float* src; __bf16* dst; size_t off;
    if (uid < 2097152)      { src = x;   dst = xb;  off = uid; }
    else if (uid < 4194304) { src = y;   dst = yb;  off = uid - 2097152; }
    else if (uid < 4325376) { src = wqf; dst = wqb; off = uid - 4194304; }
    else if (uid < 4456448) { src = wkf; dst = wkb; off = uid - 4325376; }
    else                    { src = wvf; dst = wvb; off = uid - 4456448; }
    float4 a = ((const float4*)src)[off * 2];
    float4 b = ((const float4*)src)[off * 2 + 1];
    *(bf16x8*)(dst + off * 8) = pack8(a, b);
}

// ---------------------------------------------------------------------------
// bf16 GEMM: C[8192,512] = A_bf16[8192,2048] @ B_bf16[512,2048]^T  (z: q/k/v)
// 128x128 tile, BK=64, 256 thr, register-prefetch of next chunk.
// ---------------------------------------------------------------------------
__global__ __launch_bounds__(256, 3) void gemm_qkv_bf16(
    const __bf16* __restrict__ xb, const __bf16* __restrict__ yb,
    const __bf16* __restrict__ wq, const __bf16* __restrict__ wk,
    const __bf16* __restrict__ wv, __bf16* __restrict__ qo,
    __bf16* __restrict__ ko, __bf16* __restrict__ vo)
{
    constexpr int K = 2048, N = 512;
    __shared__ __bf16 As[128][72];
    __shared__ __bf16 Bs[128][72];

    const int z = blockIdx.z;
    const __bf16* A = (z == 0) ? xb : yb;
    const __bf16* B = (z == 0) ? wq : (z == 1) ? wk : wv;
    __bf16* C = (z == 0) ? qo : (z == 1) ? ko : vo;

    const int tid  = threadIdx.x;
    const int wave = tid >> 6, lane = tid & 63;
    const int fr = lane & 15, fq = lane >> 4;
    const int m0 = blockIdx.x * 128;
    const int n0 = blockIdx.y * 128;
    const int wr = (wave >> 1) * 64, wc = (wave & 1) * 64;
    const int srow  = tid >> 1;          // 0..127
    const int shalf = (tid & 1) * 32;    // 0 or 32

    f32x4 acc[4][4];
#pragma unroll
    for (int a = 0; a < 4; ++a)
#pragma unroll
        for (int b = 0; b < 4; ++b) acc[a][b] = f32x4{0.f, 0.f, 0.f, 0.f};

    const __bf16* ap = A + (size_t)(m0 + srow) * K + shalf;
    const __bf16* bp = B + (size_t)(n0 + srow) * K + shalf;

    bf16x8 ab[4], bb[4];
#pragma unroll
    for (int u = 0; u < 4; ++u) { ab[u] = ((const bf16x8*)ap)[u]; bb[u] = ((const bf16x8*)bp)[u]; }

    for (int kk = 0; kk < K; kk += 64) {
        __syncthreads();
#pragma unroll
        for (int u = 0; u < 4; ++u) {
            *(bf16x8*)&As[srow][shalf + u * 8] = ab[u];
            *(bf16x8*)&Bs[srow][shalf + u * 8] = bb[u];
        }
        __syncthreads();
        if (kk + 64 < K) {
#pragma unroll
            for (int u = 0; u < 4; ++u) {
                ab[u] = ((const bf16x8*)(ap + kk + 64))[u];
                bb[u] = ((const bf16x8*)(bp + kk + 64))[u];
            }
        }
#pragma unroll
        for (int ks = 0; ks < 2; ++ks) {
            bf16x8 af[4], bf[4];
#pragma unroll
            for (int rt = 0; rt < 4; ++rt)
                af[rt] = *(const bf16x8*)&As[wr + rt * 16 + fr][ks * 32 + fq * 8];
#pragma unroll
            for (int nt = 0; nt < 4; ++nt)
                bf[nt] = *(const bf16x8*)&Bs[wc + nt * 16 + fr][ks * 32 + fq * 8];
#pragma unroll
            for (int rt = 0; rt < 4; ++rt)
#pragma unroll
                for (int nt = 0; nt < 4; ++nt)
                    acc[rt][nt] = MFMA16(af[rt], bf[nt], acc[rt][nt]);
        }
    }

#pragma unroll
    for (int rt = 0; rt < 4; ++rt)
#pragma unroll
        for (int nt = 0; nt < 4; ++nt) {
            const int col = n0 + wc + nt * 16 + fr;
#pragma unroll
            for (int r = 0; r < 4; ++r) {
                const int row = m0 + wr + rt * 16 + fq * 4 + r;
                C[(size_t)row * N + col] = (__bf16)acc[rt][nt][r];
            }
        }
}

// ---------------------------------------------------------------------------
// Transpose v[8192,512] -> vT[512,8192] (bf16), 64x64 LDS tiles.
// ---------------------------------------------------------------------------
__global__ __launch_bounds__(256) void transpose_v(
    const ushort* __restrict__ v, ushort* __restrict__ vT)
{
    __shared__ ushort tile[64][72];
    const int t = threadIdx.x;
    const int r0 = blockIdx.x * 64;
    const int c0 = blockIdx.y * 64;
    const int lr = t >> 2;
    const int lc = (t & 3) * 16;

    union { float4 f[2]; ushort s[16]; } u;
    const float4* vp = (const float4*)(v + (size_t)(r0 + lr) * 512 + c0 + lc);
    u.f[0] = vp[0];
    u.f[1] = vp[1];
#pragma unroll
    for (int e = 0; e < 16; ++e) tile[lc + e][lr] = u.s[e];
    __syncthreads();
    float4* op = (float4*)(vT + (size_t)(c0 + lr) * 8192 + r0 + lc);
    op[0] = *(const float4*)&tile[lr][lc];
    op[1] = *(const float4*)&tile[lr][lc + 8];
}

// ---------------------------------------------------------------------------
// S kernel: banded masked scores. Block = lower-tri tile (t,j), 2080 blocks.
// S_tile = q[t] @ k[j]^T * SCALE, strict-lower mask on diagonal tiles,
// bf16 row-major 128x128 tile stored at Sb + lin*16384.
// ---------------------------------------------------------------------------
__global__ __launch_bounds__(256, 3) void s_gemm(
    const __bf16* __restrict__ q, const __bf16* __restrict__ k,
    __bf16* __restrict__ Sb)
{
    constexpr int K = 512;
    __shared__ __bf16 As[128][72];
    __shared__ __bf16 Bs[128][72];

    const int lin = blockIdx.x;
    int t = (int)((sqrtf(8.0f * lin + 1.0f) - 1.0f) * 0.5f);
    while ((t + 1) * (t + 2) / 2 <= lin) ++t;
    while (t * (t + 1) / 2 > lin) --t;
    const int j = lin - t * (t + 1) / 2;

    const int tid  = threadIdx.x;
    const int wave = tid >> 6, lane = tid & 63;
    const int fr = lane & 15, fq = lane >> 4;
    const int wr = (wave >> 1) * 64, wc = (wave & 1) * 64;
    const int srow  = tid >> 1;
    const int shalf = (tid & 1) * 32;

    f32x4 acc[4][4];
#pragma unroll
    for (int a = 0; a < 4; ++a)
#pragma unroll
        for (int b = 0; b < 4; ++b) acc[a][b] = f32x4{0.f, 0.f, 0.f, 0.f};

    const __bf16* ap = q + (size_t)(t * 128 + srow) * K + shalf;
    const __bf16* bp = k + (size_t)(j * 128 + srow) * K + shalf;

    bf16x8 ab[4], bb[4];
#pragma unroll
    for (int u = 0; u < 4; ++u) { ab[u] = ((const bf16x8*)ap)[u]; bb[u] = ((const bf16x8*)bp)[u]; }

    for (int kk = 0; kk < K; kk += 64) {
        __syncthreads();
#pragma unroll
        for (int u = 0; u < 4; ++u) {
            *(bf16x8*)&As[srow][shalf + u * 8] = ab[u];
            *(bf16x8*)&Bs[srow][shalf + u * 8] = bb[u];
        }
        __syncthreads();
        if (kk + 64 < K) {
#pragma unroll
            for (int u = 0; u < 4; ++u) {
                ab[u] = ((const bf16x8*)(ap + kk + 64))[u];
                bb[u] = ((const bf16x8*)(bp + kk + 64))[u];
            }
        }
#pragma unroll
        for (int ks = 0; ks < 2; ++ks) {
            bf16x8 af[4], bf[4];
#pragma unroll
            for (int rt = 0; rt < 4; ++rt)
                af[rt] = *(const bf16x8*)&As[wr + rt * 16 + fr][ks * 32 + fq * 8];
#pragma unroll
            for (int nt = 0; nt < 4; ++nt)
                bf[nt] = *(const bf16x8*)&Bs[wc + nt * 16 + fr][ks * 32 + fq * 8];
#pragma unroll
            for (int rt = 0; rt < 4; ++rt)
#pragma unroll
                for (int nt = 0; nt < 4; ++nt)
                    acc[rt][nt] = MFMA16(af[rt], bf[nt], acc[rt][nt]);
        }
    }

    __bf16* tp = Sb + (size_t)lin * 16384;
    const bool diag = (t == j);
#pragma unroll
    for (int rt = 0; rt < 4; ++rt)
#pragma unroll
        for (int nt = 0; nt < 4; ++nt) {
            const int col = wc + nt * 16 + fr;
#pragma unroll
            for (int r = 0; r < 4; ++r) {
                const int row = wr + rt * 16 + fq * 4 + r;
                float vv = acc[rt][nt][r] * SCALE;
                if (diag && col >= row) vv = 0.f;
                tp[row * 128 + col] = (__bf16)vv;
            }
        }
}

// ---------------------------------------------------------------------------
// PV kernel: out[128x128 tile] += S_band(t, jseg) @ V.  B^T = vT[512][8192].
// blockIdx.x = lin over (t desc, seg asc), 160 total; blockIdx.y = n-tile (4).
// K-segment = up to 16 j-tiles (2048 K). fp32 atomicAdd epilogue.
// ---------------------------------------------------------------------------
__global__ __launch_bounds__(256, 3) void pv_gemm(
    const __bf16* __restrict__ Sb, const __bf16* __restrict__ vT,
    float* __restrict__ out)
{
    __shared__ __bf16 As[128][72];
    __shared__ __bf16 Bs[128][72];

    int rem = blockIdx.x;
    int t = 63;
    while (true) {
        int ns = (t + 16) >> 4;
        if (rem < ns) break;
        rem -= ns; --t;
    }
    const int seg = rem;
    const int j0 = seg * 16;
    const int j1 = min(j0 + 15, t);
    const int nchunk = (j1 - j0 + 1) * 2;
    const int tb = t * (t + 1) / 2;
    const int n0 = blockIdx.y * 128;

    const int tid  = threadIdx.x;
    const int wave = tid >> 6, lane = tid & 63;
    const int fr = lane & 15, fq = lane >> 4;
    const int wr = (wave >> 1) * 64, wc = (wave & 1) * 64;
    const int srow  = tid >> 1;
    const int shalf = (tid & 1) * 32;

    f32x4 acc[4][4];
#pragma unroll
    for (int a = 0; a < 4; ++a)
#pragma unroll
        for (int b = 0; b < 4; ++b) acc[a][b] = f32x4{0.f, 0.f, 0.f, 0.f};

    const __bf16* brow = vT + (size_t)(n0 + srow) * 8192 + shalf;

    bf16x8 ab[4], bb[4];
    {
        const __bf16* a0 = Sb + (size_t)(tb + j0) * 16384 + srow * 128 + shalf;
        const __bf16* b0 = brow + (size_t)j0 * 128;
#pragma unroll
        for (int u = 0; u < 4; ++u) { ab[u] = ((const bf16x8*)a0)[u]; bb[u] = ((const bf16x8*)b0)[u]; }
    }

    for (int c = 0; c < nchunk; ++c) {
        __syncthreads();
#pragma unroll
        for (int u = 0; u < 4; ++u) {
            *(bf16x8*)&As[srow][shalf + u * 8] = ab[u];
            *(bf16x8*)&Bs[srow][shalf + u * 8] = bb[u];
        }
        __syncthreads();
        if (c + 1 < nchunk) {
            const int cn = c + 1;
            const int jn = j0 + (cn >> 1);
            const int ho = (cn & 1) * 64;
            const __bf16* an = Sb + (size_t)(tb + jn) * 16384 + srow * 128 + ho + shalf;
            const __bf16* bn = brow + (size_t)jn * 128 + ho;
#pragma unroll
            for (int u = 0; u < 4; ++u) { ab[u] = ((const bf16x8*)an)[u]; bb[u] = ((const bf16x8*)bn)[u]; }
        }
#pragma unroll
        for (int ks = 0; ks < 2; ++ks) {
            bf16x8 af[4], bf[4];
#pragma unroll
            for (int rt = 0; rt < 4; ++rt)
                af[rt] = *(const bf16x8*)&As[wr + rt * 16 + fr][ks * 32 + fq * 8];
#pragma unroll
            for (int nt = 0; nt < 4; ++nt)
                bf[nt] = *(const bf16x8*)&Bs[wc + nt * 16 + fr][ks * 32 + fq * 8];
#pragma unroll
            for (int rt = 0; rt < 4; ++rt)
#pragma unroll
                for (int nt = 0; nt < 4; ++nt)
                    acc[rt][nt] = MFMA16(af[rt], bf[nt], acc[rt][nt]);
        }
    }

#pragma unroll
    for (int rt = 0; rt < 4; ++rt)
#pragma unroll
        for (int nt = 0; nt < 4; ++nt) {
            const int col = n0 + wc + nt * 16 + fr;
#pragma unroll
            for (int r = 0; r < 4; ++r) {
                const int row = t * 128 + wr + rt * 16 + fq * 4 + r;
                atomicAdd(&out[(size_t)row * 512 + col], acc[rt][nt][r]);
            }
        }
}

// ======================= FALLBACK (R3 pipeline) if ws too small =============
__global__ __launch_bounds__(256, 2) void gemm_qkv3(
    const float* __restrict__ x, const float* __restrict__ y,
    const float* __restrict__ Wq, const float* __restrict__ Wk,
    const float* __restrict__ Wv, __bf16* __restrict__ qo,
    __bf16* __restrict__ ko, __bf16* __restrict__ vo)
{
    constexpr int K = 2048, N = 512;
    __shared__ __bf16 As[128][72];
    __shared__ __bf16 Bs[128][72];
    const int z = blockIdx.z;
    const float* A = (z == 0) ? x : y;
    const float* B = (z == 0) ? Wq : (z == 1) ? Wk : Wv;
    __bf16* C = (z == 0) ? qo : (z == 1) ? ko : vo;
    const int tid  = threadIdx.x;
    const int wave = tid >> 6, lane = tid & 63;
    const int fr = lane & 15, fq = lane >> 4;
    const int m0 = blockIdx.x * 128, n0 = blockIdx.y * 128;
    const int wr = (wave >> 1) * 64, wc = (wave & 1) * 64;
    const int srow = tid >> 1, scol = (tid & 1) * 32;
    f32x4 acc[4][4];
#pragma unroll
    for (int a = 0; a < 4; ++a)
#pragma unroll
        for (int b = 0; b < 4; ++b) acc[a][b] = f32x4{0.f, 0.f, 0.f, 0.f};
    const float* ap = A + (size_t)(m0 + srow) * K + scol;
    const float* bp = B + (size_t)(n0 + srow) * K + scol;
    float4 av[8], bv[8];
#pragma unroll
    for (int u = 0; u < 8; ++u) av[u] = ((const float4*)ap)[u];
#pragma unroll
    for (int u = 0; u < 8; ++u) bv[u] = ((const float4*)bp)[u];
    for (int kk = 0; kk < K; kk += 64) {
        __syncthreads();
#pragma unroll
        for (int u = 0; u < 4; ++u) {
            *(bf16x8*)&As[srow][scol + u * 8] = pack8(av[2 * u], av[2 * u + 1]);
            *(bf16x8*)&Bs[srow][scol + u * 8] = pack8(bv[2 * u], bv[2 * u + 1]);
        }
        __syncthreads();
        if (kk + 64 < K) {
#pragma unroll
            for (int u = 0; u < 8; ++u) av[u] = ((const float4*)(ap + kk + 64))[u];
#pragma unroll
            for (int u = 0; u < 8; ++u) bv[u] = ((const float4*)(bp + kk + 64))[u];
        }
#pragma unroll
        for (int ks = 0; ks < 2; ++ks) {
            bf16x8 af[4], bf[4];
#pragma unroll
            for (int rt = 0; rt < 4; ++rt)
                af[rt] = *(const bf16x8*)&As[wr + rt * 16 + fr][ks * 32 + fq * 8];
#pragma unroll
            for (int nt = 0; nt < 4; ++nt)
                bf[nt] = *(const bf16x8*)&Bs[wc + nt * 16 + fr][ks * 32 + fq * 8];
#pragma unroll
            for (int rt = 0; rt < 4; ++rt)
#pragma unroll
                for (int nt = 0; nt < 4; ++nt)
                    acc[rt][nt] = MFMA16(af[rt], bf[nt], acc[rt][nt]);
        }
    }
#pragma unroll
    for (int rt = 0; rt < 4; ++rt)
#pragma unroll
        for (int nt = 0; nt < 4; ++nt) {
            const int col = n0 + wc + nt * 16 + fr;
#pragma unroll
            for (int r = 0; r < 4; ++r) {
                const int row = m0 + wr + rt * 16 + fq * 4 + r;
                C[(size_t)row * N + col] = (__bf16)acc[rt][nt][r];
            }
        }
}

__global__ __launch_bounds__(512, 1) void fused_av(
    const __bf16* __restrict__ q, const __bf16* __restrict__ k,
    const __bf16* __restrict__ vT, float* __restrict__ out)
{
    extern __shared__ __bf16 smem[];
    __bf16 (*qs)[136] = (__bf16(*)[136])smem;
    __bf16 (*ks)[136] = (__bf16(*)[136])(smem + 128 * 136);
    __bf16 (*ps)[136] = (__bf16(*)[136])smem;
    const int tid  = threadIdx.x;
    const int wave = tid >> 6, lane = tid & 63;
    const int fr = lane & 15, fq = lane >> 4;
    const int wr = (wave >> 2) * 64;
    const int wc = (wave & 3) * 32;
    const int oc = (wave & 3) * 128;
    int rem = blockIdx.x;
    int t = 63, nb;
    while (true) {
        nb = (t + 8) >> 3;
        if (rem < nb) break;
        rem -= nb; --t;
    }
    const int s = rem;
    const int r0 = tid >> 4, blk = tid & 15;
    f32x4 acc_o[4][8];
#pragma unroll
    for (int rt = 0; rt < 4; ++rt)
#pragma unroll
        for (int nt = 0; nt < 8; ++nt) acc_o[rt][nt] = f32x4{0.f, 0.f, 0.f, 0.f};
    for (int j = s; j <= t; j += nb) {
        f32x4 acc_s[4][2];
#pragma unroll
        for (int rt = 0; rt < 4; ++rt)
#pragma unroll
            for (int ct = 0; ct < 2; ++ct) acc_s[rt][ct] = f32x4{0.f, 0.f, 0.f, 0.f};
        bf16x8 qreg[4], kreg[4];
#pragma unroll
        for (int u = 0; u < 4; ++u) {
            qreg[u] = *(const bf16x8*)(q + (size_t)(t * 128 + r0 + 32 * u) * 512 + blk * 8);
            kreg[u] = *(const bf16x8*)(k + (size_t)(j * 128 + r0 + 32 * u) * 512 + blk * 8);
        }
#pragma unroll
        for (int ii = 0; ii < 4; ++ii) {
            __syncthreads();
#pragma unroll
            for (int u = 0; u < 4; ++u) {
                *(bf16x8*)&qs[r0 + 32 * u][blk * 8] = qreg[u];
                *(bf16x8*)&ks[r0 + 32 * u][blk * 8] = kreg[u];
            }
            __syncthreads();
            if (ii < 3) {
                const int kk = (ii + 1) * 128;
#pragma unroll
                for (int u = 0; u < 4; ++u) {
                    qreg[u] = *(const bf16x8*)(q + (size_t)(t * 128 + r0 + 32 * u) * 512 + kk + blk * 8);
                    kreg[u] = *(const bf16x8*)(k + (size_t)(j * 128 + r0 + 32 * u) * 512 + kk + blk * 8);
                }
            }
#pragma unroll
            for (int ksC = 0; ksC < 4; ++ksC) {
                bf16x8 af[4], bfg[2];
#pragma unroll
                for (int rt = 0; rt < 4; ++rt)
                    af[rt] = *(const bf16x8*)&qs[wr + rt * 16 + fr][ksC * 32 + fq * 8];
#pragma unroll
                for (int ct = 0; ct < 2; ++ct)
                    bfg[ct] = *(const bf16x8*)&ks[wc + ct * 16 + fr][ksC * 32 + fq * 8];
#pragma unroll
                for (int rt = 0; rt < 4; ++rt)
#pragma unroll
                    for (int ct = 0; ct < 2; ++ct)
                        acc_s[rt][ct] = MFMA16(af[rt], bfg[ct], acc_s[rt][ct]);
            }
        }
        __syncthreads();
#pragma unroll
        for (int rt = 0; rt < 4; ++rt)
#pragma unroll
            for (int ct = 0; ct < 2; ++ct) {
                const int col  = wc + ct * 16 + fr;
                const int gcol = j * 128 + col;
#pragma unroll
                for (int r = 0; r < 4; ++r) {
                    const int row  = wr + rt * 16 + fq * 4 + r;
                    const int grow = t * 128 + row;
                    ps[row][col] = (__bf16)((gcol >= grow) ? 0.f : acc_s[rt][ct][r] * SCALE);
                }
            }
        __syncthreads();
#pragma unroll
        for (int c2 = 0; c2 < 4; ++c2) {
            bf16x8 pf[4], vf[8];
#pragma unroll
            for (int nt = 0; nt < 8; ++nt)
                vf[nt] = *(const bf16x8*)(vT + (size_t)(oc + nt * 16 + fr) * 8192
                                          + j * 128 + c2 * 32 + fq * 8);
#pragma unroll
            for (int rt = 0; rt < 4; ++rt)
                pf[rt] = *(const bf16x8*)&ps[wr + rt * 16 + fr][c2 * 32 + fq * 8];
#pragma unroll
            for (int rt = 0; rt < 4; ++rt)
#pragma unroll
                for (int nt = 0; nt < 8; ++nt)
                    acc_o[rt][nt] = MFMA16(pf[rt], vf[nt], acc_o[rt][nt]);
        }
    }
#pragma unroll
    for (int rt = 0; rt < 4; ++rt)
#pragma unroll
        for (int nt = 0; nt < 8; ++nt) {
            const int col = oc + nt * 16 + fr;
#pragma unroll
            for (int r = 0; r < 4; ++r) {
                const int row = t * 128 + wr + rt * 16 + fq * 4 + r;
                atomicAdd(&out[(size_t)row * 512 + col], acc_o[rt][nt][r]);
            }
        }
}

// ---------------------------------------------------------------------------
extern "C" void kernel_launch(void* const* d_in, const int* in_sizes, int n_in,
                              void* d_out, int out_size, void* d_ws, size_t ws_size,
                              hipStream_t stream) {
    const float* x  = (const float*)d_in[0];
    const float* y  = (const float*)d_in[1];
    const float* Wq = (const float*)d_in[2];
    const float* Wk = (const float*)d_in[3];
    const float* Wv = (const float*)d_in[4];
    float* out = (float*)d_out;

    const size_t QK = (size_t)8192 * 512;       // 4194304
    __bf16* q  = (__bf16*)d_ws;
    __bf16* k  = q + QK;
    __bf16* v  = k + QK;
    __bf16* vT = v + QK;

    hipMemsetAsync(d_out, 0, QK * sizeof(float), stream);

    const size_t need = (size_t)(16777216 + 2 * 16777216 + 3 * 1048576) * 2; // 102 MB

    if (ws_size >= need) {
        __bf16* xb  = vT + QK;                  // elem 16777216
        __bf16* yb  = xb + 16777216;
        __bf16* wqb = yb + 16777216;
        __bf16* wkb = wqb + 1048576;
        __bf16* wvb = wkb + 1048576;
        __bf16* Sb  = xb;                       // overlaps xb.. (dead after gemm)

        convert_all<<<17920, 256, 0, stream>>>(x, y, Wq, Wk, Wv, xb, yb, wqb, wkb, wvb);
        gemm_qkv_bf16<<<dim3(64, 4, 3), 256, 0, stream>>>(xb, yb, wqb, wkb, wvb, q, k, v);
        transpose_v<<<dim3(128, 8), 256, 0, stream>>>((const ushort*)v, (ushort*)vT);
        s_gemm<<<2080, 256, 0, stream>>>(q, k, Sb);
        pv_gemm<<<dim3(160, 4), 256, 0, stream>>>(Sb, vT, out);
    } else {
        gemm_qkv3<<<dim3(64, 4, 3), 256, 0, stream>>>(x, y, Wq, Wk, Wv, q, k, v);
        transpose_v<<<dim3(128, 8), 256, 0, stream>>>((const ushort*)v, (ushort*)vT);
        const int fused_lds = 2 * 128 * 136 * sizeof(__bf16);
        hipFuncSetAttribute((const void*)fused_av,
                            hipFuncAttributeMaxDynamicSharedMemorySize, fused_lds);
        fused_av<<<288, 512, fused_lds, stream>>>(q, k, vT, out);
    }
}

// Round 5
// 336.134 us; speedup vs baseline: 2.3295x; 1.0937x over previous
//
#include <hip/hip_runtime.h>
#include <hip/hip_bf16.h>

// q = x@Wq^T; k = y@Wk^T; v = y@Wv^T; out = strict_lower(q@k^T * D^-0.5) @ v
// NX=NY=8192, C=2048, D=512. bf16 MFMA everywhere.
//
// v5: all GEMM kernels use the m97 structure: async global_load_lds width=16
// into unpadded [128][64] LDS tiles, XOR-swizzled chunk order (swizzle applied
// to the per-lane GLOBAL source address; LDS dst is wave-uniform base+lane*16).
// Pipeline: convert -> gemm_qkv -> transpose_v -> s_gemm (banded S) -> pv_gemm.
// ws (bf16 elems): q[4M] k[4M] v[4M] vT[4M] | xb[16M] yb[16M] wq/wk/wv[1M x3]
//   Sb (2080 tiles * 16384) overlaps xb.. (dead after gemm). Peak ~102 MB.

typedef __bf16 bf16x8 __attribute__((ext_vector_type(8)));
typedef float f32x4 __attribute__((ext_vector_type(4)));

#define MFMA16(a, b, c) __builtin_amdgcn_mfma_f32_16x16x32_bf16(a, b, c, 0, 0, 0)

constexpr float SCALE = 0.04419417382415922f; // 1/sqrt(512)

__device__ __forceinline__ void ld16(const void* g, void* l) {
    __builtin_amdgcn_global_load_lds(
        (__attribute__((address_space(1))) void*)g,
        (__attribute__((address_space(3))) void*)l, 16, 0, 0);
}

// read data-chunk c (16B) of row r from a [128][64] bf16 tile stored with
// slot = c ^ (r&7) swizzle. base = &S[0][0].
__device__ __forceinline__ bf16x8 frag(const __bf16* base, int r, int c) {
    return *(const bf16x8*)((const char*)base + r * 128 + ((c ^ (r & 7)) * 16));
}

__device__ inline bf16x8 pack8(float4 a, float4 b) {
    bf16x8 r;
    r[0] = (__bf16)a.x; r[1] = (__bf16)a.y; r[2] = (__bf16)a.z; r[3] = (__bf16)a.w;
    r[4] = (__bf16)b.x; r[5] = (__bf16)b.y; r[6] = (__bf16)b.z; r[7] = (__bf16)b.w;
    return r;
}

// ---------------------------------------------------------------------------
// fp32 -> bf16 conversion, one launch. unit = 8 floats.
// x: 2097152 units, y: 2097152, Wq/Wk/Wv: 131072 each. total 4587520 = 17920*256
// ---------------------------------------------------------------------------
__global__ __launch_bounds__(256) void convert_all(
    const float* __restrict__ x, const float* __restrict__ y,
    const float* __restrict__ wqf, const float* __restrict__ wkf,
    const float* __restrict__ wvf, __bf16* __restrict__ xb,
    __bf16* __restrict__ yb, __bf16* __restrict__ wqb,
    __bf16* __restrict__ wkb, __bf16* __restrict__ wvb)
{
    size_t uid = (size_t)blockIdx.x * 256 + threadIdx.x;
    const float* src; __bf16* dst; size_t off;
    if (uid < 2097152)      { src = x;   dst = xb;  off = uid; }
    else if (uid < 4194304) { src = y;   dst = yb;  off = uid - 2097152; }
    else if (uid < 4325376) { src = wqf; dst = wqb; off = uid - 4194304; }
    else if (uid < 4456448) { src = wkf; dst = wkb; off = uid - 4325376; }
    else                    { src = wvf; dst = wvb; off = uid - 4456448; }
    float4 a = ((const float4*)src)[off * 2];
    float4 b = ((const float4*)src)[off * 2 + 1];
    *(bf16x8*)(dst + off * 8) = pack8(a, b);
}

// ---------------------------------------------------------------------------
// bf16 GEMM: C[8192,512] = A[8192,2048] @ B[512,2048]^T  (z selects q/k/v).
// 128x128 tile, BK=64, async LDS staging. Wave w stages rows [w*32,w*32+32).
// ---------------------------------------------------------------------------
__global__ __launch_bounds__(256, 3) void gemm_qkv_bf16(
    const __bf16* __restrict__ xb, const __bf16* __restrict__ yb,
    const __bf16* __restrict__ wq, const __bf16* __restrict__ wk,
    const __bf16* __restrict__ wv, __bf16* __restrict__ qo,
    __bf16* __restrict__ ko, __bf16* __restrict__ vo)
{
    constexpr int K = 2048, N = 512;
    __shared__ __align__(16) __bf16 As[128][64];
    __shared__ __align__(16) __bf16 Bs[128][64];

    const int z = blockIdx.z;
    const __bf16* A = (z == 0) ? xb : yb;
    const __bf16* B = (z == 0) ? wq : (z == 1) ? wk : wv;
    __bf16* C = (z == 0) ? qo : (z == 1) ? ko : vo;

    const int tid  = threadIdx.x;
    const int wave = tid >> 6, lane = tid & 63;
    const int fr = lane & 15, fq = lane >> 4;
    const int m0 = blockIdx.x * 128, n0 = blockIdx.y * 128;
    const int wr = (wave >> 1) * 64, wc = (wave & 1) * 64;
    const int lr = lane >> 3;            // row within 8-row group
    const int cd = (lane & 7) ^ lr;      // XOR-swizzled source chunk

    f32x4 acc[4][4];
#pragma unroll
    for (int a = 0; a < 4; ++a)
#pragma unroll
        for (int b = 0; b < 4; ++b) acc[a][b] = f32x4{0.f, 0.f, 0.f, 0.f};

    const __bf16* ag = A + (size_t)(m0 + wave * 32 + lr) * K + cd * 8;
    const __bf16* bg = B + (size_t)(n0 + wave * 32 + lr) * K + cd * 8;
    __bf16* al = &As[wave * 32][0];
    __bf16* bl = &Bs[wave * 32][0];

    for (int kk = 0; kk < K; kk += 64) {
        __syncthreads();                 // prev step's frag reads done
#pragma unroll
        for (int u = 0; u < 4; ++u) {
            ld16(ag + (size_t)(u * 8) * K + kk, al + u * 512);
            ld16(bg + (size_t)(u * 8) * K + kk, bl + u * 512);
        }
        __syncthreads();                 // drains vmcnt: tiles visible
#pragma unroll
        for (int ks = 0; ks < 2; ++ks) {
            bf16x8 af[4], bf[4];
#pragma unroll
            for (int rt = 0; rt < 4; ++rt)
                af[rt] = frag(&As[0][0], wr + rt * 16 + fr, ks * 4 + fq);
#pragma unroll
            for (int nt = 0; nt < 4; ++nt)
                bf[nt] = frag(&Bs[0][0], wc + nt * 16 + fr, ks * 4 + fq);
#pragma unroll
            for (int rt = 0; rt < 4; ++rt)
#pragma unroll
                for (int nt = 0; nt < 4; ++nt)
                    acc[rt][nt] = MFMA16(af[rt], bf[nt], acc[rt][nt]);
        }
    }

#pragma unroll
    for (int rt = 0; rt < 4; ++rt)
#pragma unroll
        for (int nt = 0; nt < 4; ++nt) {
            const int col = n0 + wc + nt * 16 + fr;
#pragma unroll
            for (int r = 0; r < 4; ++r) {
                const int row = m0 + wr + rt * 16 + fq * 4 + r;
                C[(size_t)row * N + col] = (__bf16)acc[rt][nt][r];
            }
        }
}

// ---------------------------------------------------------------------------
// Transpose v[8192,512] -> vT[512,8192] (bf16), 64x64 LDS tiles.
// ---------------------------------------------------------------------------
__global__ __launch_bounds__(256) void transpose_v(
    const ushort* __restrict__ v, ushort* __restrict__ vT)
{
    __shared__ ushort tile[64][72];
    const int t = threadIdx.x;
    const int r0 = blockIdx.x * 64;
    const int c0 = blockIdx.y * 64;
    const int lr = t >> 2;
    const int lc = (t & 3) * 16;

    union { float4 f[2]; ushort s[16]; } u;
    const float4* vp = (const float4*)(v + (size_t)(r0 + lr) * 512 + c0 + lc);
    u.f[0] = vp[0];
    u.f[1] = vp[1];
#pragma unroll
    for (int e = 0; e < 16; ++e) tile[lc + e][lr] = u.s[e];
    __syncthreads();
    float4* op = (float4*)(vT + (size_t)(c0 + lr) * 8192 + r0 + lc);
    op[0] = *(const float4*)&tile[lr][lc];
    op[1] = *(const float4*)&tile[lr][lc + 8];
}

// ---------------------------------------------------------------------------
// S kernel: banded masked scores. Block = lower-tri tile (t,j), 2080 blocks.
// S_tile = q[t] @ k[j]^T * SCALE (strict-lower mask on diagonal tiles),
// bf16 row-major 128x128 tile at Sb + lin*16384. K=512, async staging.
// ---------------------------------------------------------------------------
__global__ __launch_bounds__(256, 3) void s_gemm(
    const __bf16* __restrict__ q, const __bf16* __restrict__ k,
    __bf16* __restrict__ Sb)
{
    constexpr int K = 512;
    __shared__ __align__(16) __bf16 As[128][64];
    __shared__ __align__(16) __bf16 Bs[128][64];

    const int lin = blockIdx.x;
    int t = (int)((sqrtf(8.0f * lin + 1.0f) - 1.0f) * 0.5f);
    while ((t + 1) * (t + 2) / 2 <= lin) ++t;
    while (t * (t + 1) / 2 > lin) --t;
    const int j = lin - t * (t + 1) / 2;

    const int tid  = threadIdx.x;
    const int wave = tid >> 6, lane = tid & 63;
    const int fr = lane & 15, fq = lane >> 4;
    const int wr = (wave >> 1) * 64, wc = (wave & 1) * 64;
    const int lr = lane >> 3;
    const int cd = (lane & 7) ^ lr;

    f32x4 acc[4][4];
#pragma unroll
    for (int a = 0; a < 4; ++a)
#pragma unroll
        for (int b = 0; b < 4; ++b) acc[a][b] = f32x4{0.f, 0.f, 0.f, 0.f};

    const __bf16* ag = q + (size_t)(t * 128 + wave * 32 + lr) * K + cd * 8;
    const __bf16* bg = k + (size_t)(j * 128 + wave * 32 + lr) * K + cd * 8;
    __bf16* al = &As[wave * 32][0];
    __bf16* bl = &Bs[wave * 32][0];

    for (int kk = 0; kk < K; kk += 64) {
        __syncthreads();
#pragma unroll
        for (int u = 0; u < 4; ++u) {
            ld16(ag + (size_t)(u * 8) * K + kk, al + u * 512);
            ld16(bg + (size_t)(u * 8) * K + kk, bl + u * 512);
        }
        __syncthreads();
#pragma unroll
        for (int ks = 0; ks < 2; ++ks) {
            bf16x8 af[4], bf[4];
#pragma unroll
            for (int rt = 0; rt < 4; ++rt)
                af[rt] = frag(&As[0][0], wr + rt * 16 + fr, ks * 4 + fq);
#pragma unroll
            for (int nt = 0; nt < 4; ++nt)
                bf[nt] = frag(&Bs[0][0], wc + nt * 16 + fr, ks * 4 + fq);
#pragma unroll
            for (int rt = 0; rt < 4; ++rt)
#pragma unroll
                for (int nt = 0; nt < 4; ++nt)
                    acc[rt][nt] = MFMA16(af[rt], bf[nt], acc[rt][nt]);
        }
    }

    __bf16* tp = Sb + (size_t)lin * 16384;
    const bool diag = (t == j);
#pragma unroll
    for (int rt = 0; rt < 4; ++rt)
#pragma unroll
        for (int nt = 0; nt < 4; ++nt) {
            const int col = wc + nt * 16 + fr;
#pragma unroll
            for (int r = 0; r < 4; ++r) {
                const int row = wr + rt * 16 + fq * 4 + r;
                float vv = acc[rt][nt][r] * SCALE;
                if (diag && col >= row) vv = 0.f;
                tp[row * 128 + col] = (__bf16)vv;
            }
        }
}

// ---------------------------------------------------------------------------
// PV kernel: out[128x128 tile] += S_band(t, jseg) @ V.  B^T = vT[512][8192].
// blockIdx.x = lin over (t desc, seg asc), 160 total; blockIdx.y = n-tile (4).
// K-segment = up to 16 j-tiles (2048 K). fp32 atomicAdd epilogue.
// ---------------------------------------------------------------------------
__global__ __launch_bounds__(256, 3) void pv_gemm(
    const __bf16* __restrict__ Sb, const __bf16* __restrict__ vT,
    float* __restrict__ out)
{
    __shared__ __align__(16) __bf16 As[128][64];
    __shared__ __align__(16) __bf16 Bs[128][64];

    int rem = blockIdx.x;
    int t = 63;
    while (true) {
        int ns = (t + 16) >> 4;
        if (rem < ns) break;
        rem -= ns; --t;
    }
    const int seg = rem;
    const int j0 = seg * 16;
    const int j1 = min(j0 + 15, t);
    const int nchunk = (j1 - j0 + 1) * 2;
    const int tb = t * (t + 1) / 2;
    const int n0 = blockIdx.y * 128;

    const int tid  = threadIdx.x;
    const int wave = tid >> 6, lane = tid & 63;
    const int fr = lane & 15, fq = lane >> 4;
    const int wr = (wave >> 1) * 64, wc = (wave & 1) * 64;
    const int lr = lane >> 3;
    const int cd = (lane & 7) ^ lr;
    const int srow = wave * 32 + lr;     // staging row this lane covers (base)

    f32x4 acc[4][4];
#pragma unroll
    for (int a = 0; a < 4; ++a)
#pragma unroll
        for (int b = 0; b < 4; ++b) acc[a][b] = f32x4{0.f, 0.f, 0.f, 0.f};

    __bf16* al = &As[wave * 32][0];
    __bf16* bl = &Bs[wave * 32][0];

    for (int c = 0; c < nchunk; ++c) {
        const int jn = j0 + (c >> 1);
        const int ho = (c & 1) * 64;
        const __bf16* at = Sb + (size_t)(tb + jn) * 16384 + ho + cd * 8;
        const __bf16* bt = vT + (size_t)n0 * 8192 + jn * 128 + ho + cd * 8;
        __syncthreads();
#pragma unroll
        for (int u = 0; u < 4; ++u) {
            ld16(at + (srow + u * 8) * 128, al + u * 512);
            ld16(bt + (size_t)(srow + u * 8) * 8192, bl + u * 512);
        }
        __syncthreads();
#pragma unroll
        for (int ks = 0; ks < 2; ++ks) {
            bf16x8 af[4], bf[4];
#pragma unroll
            for (int rt = 0; rt < 4; ++rt)
                af[rt] = frag(&As[0][0], wr + rt * 16 + fr, ks * 4 + fq);
#pragma unroll
            for (int nt = 0; nt < 4; ++nt)
                bf[nt] = frag(&Bs[0][0], wc + nt * 16 + fr, ks * 4 + fq);
#pragma unroll
            for (int rt = 0; rt < 4; ++rt)
#pragma unroll
                for (int nt = 0; nt < 4; ++nt)
                    acc[rt][nt] = MFMA16(af[rt], bf[nt], acc[rt][nt]);
        }
    }

#pragma unroll
    for (int rt = 0; rt < 4; ++rt)
#pragma unroll
        for (int nt = 0; nt < 4; ++nt) {
            const int col = n0 + wc + nt * 16 + fr;
#pragma unroll
            for (int r = 0; r < 4; ++r) {
                const int row = t * 128 + wr + rt * 16 + fq * 4 + r;
                atomicAdd(&out[(size_t)row * 512 + col], acc[rt][nt][r]);
            }
        }
}

// ---------------------------------------------------------------------------
extern "C" void kernel_launch(void* const* d_in, const int* in_sizes, int n_in,
                              void* d_out, int out_size, void* d_ws, size_t ws_size,
                              hipStream_t stream) {
    const float* x  = (const float*)d_in[0];
    const float* y  = (const float*)d_in[1];
    const float* Wq = (const float*)d_in[2];
    const float* Wk = (const float*)d_in[3];
    const float* Wv = (const float*)d_in[4];
    float* out = (float*)d_out;

    const size_t QK = (size_t)8192 * 512;       // 4194304
    __bf16* q  = (__bf16*)d_ws;
    __bf16* k  = q + QK;
    __bf16* v  = k + QK;
    __bf16* vT = v + QK;
    __bf16* xb  = vT + QK;                      // 16777216 elems
    __bf16* yb  = xb + 16777216;
    __bf16* wqb = yb + 16777216;
    __bf16* wkb = wqb + 1048576;
    __bf16* wvb = wkb + 1048576;
    __bf16* Sb  = xb;                           // overlaps xb (dead after gemm)

    hipMemsetAsync(d_out, 0, QK * sizeof(float), stream);

    convert_all<<<17920, 256, 0, stream>>>(x, y, Wq, Wk, Wv, xb, yb, wqb, wkb, wvb);
    gemm_qkv_bf16<<<dim3(64, 4, 3), 256, 0, stream>>>(xb, yb, wqb, wkb, wvb, q, k, v);
    transpose_v<<<dim3(128, 8), 256, 0, stream>>>((const ushort*)v, (ushort*)vT);
    s_gemm<<<2080, 256, 0, stream>>>(q, k, Sb);
    pv_gemm<<<dim3(160, 4), 256, 0, stream>>>(Sb, vT, out);
}